// Round 14
// baseline (552.388 us; speedup 1.0000x reference)
//
#include <hip/hip_runtime.h>
#include <hip/hip_bf16.h>
#include <math.h>

#define NB 32768
#define NTOK (3 * NB)
#define NNODES 20000
#define MAXL 64

typedef short bf16x8 __attribute__((ext_vector_type(8)));
typedef float f32x4 __attribute__((ext_vector_type(4)));

typedef __attribute__((address_space(3))) void lds_t;
typedef const __attribute__((address_space(1))) void gbl_t;

__device__ __forceinline__ float b2f(short s) {
    unsigned int u = ((unsigned int)(unsigned short)s) << 16;
    union { unsigned int u; float f; } c;
    c.u = u;
    return c.f;
}

// ---------------- small setup kernels ----------------

__global__ void convert_k(const float* __restrict__ in, __hip_bfloat16* __restrict__ out, int n) {
    int i = blockIdx.x * 256 + threadIdx.x;
    int stride = gridDim.x * 256;
    for (; i < n; i += stride) out[i] = __float2bfloat16(in[i]);
}

// ff2 weights with k-dim permuted within 32-blocks so gemm1's u^T C-frags feed
// gemm2's A-frags directly in registers: src = ((p>>2)&1)*16 + ((p>>3)<<2) + (p&3)
__global__ void cvtw2_k(const float* __restrict__ in, __hip_bfloat16* __restrict__ out) {
    int idx = blockIdx.x * 256 + threadIdx.x;
    if (idx >= 2 * 128 * 512) return;
    int row = idx >> 9, kk = idx & 511;
    int s = kk >> 5, p = kk & 31;
    int src = (s << 5) + ((p >> 2) & 1) * 16 + ((p >> 3) << 2) + (p & 3);
    out[idx] = __float2bfloat16(in[(size_t)row * 512 + src]);
}

__global__ void fold12_k(const float* __restrict__ tok_w, const float* __restrict__ nl_w,
                         __hip_bfloat16* __restrict__ A12) {
    int idx = blockIdx.x * 256 + threadIdx.x;
    if (idx >= 256 * 128) return;
    int n = idx >> 7, f = idx & 127;
    const float* tw = (n < 128) ? (tok_w + n * 512) : (tok_w + (n - 128) * 512 + 128);
    float acc = 0.f;
    for (int c = 0; c < 128; ++c) acc += tw[c] * nl_w[c * 128 + f];
    A12[idx] = __float2bfloat16(acc);
}

__global__ void foldE_k(const float* __restrict__ tok_w, const float* __restrict__ el_w,
                        __hip_bfloat16* __restrict__ AE) {
    int idx = blockIdx.x * 256 + threadIdx.x;
    if (idx >= 128 * 192) return;
    int d = idx / 192, j = idx % 192;
    float acc;
    if (j < 64) {
        acc = 0.f;
        for (int c = 0; c < 128; ++c) acc += tok_w[d * 512 + 256 + c] * el_w[c * 64 + j];
    } else {
        acc = tok_w[d * 512 + 384 + (j - 64)];
    }
    AE[idx] = __float2bfloat16(acc);
}

__global__ void foldb_k(const float* __restrict__ tok_w, const float* __restrict__ tok_b,
                        const float* __restrict__ nl_b, const float* __restrict__ el_b,
                        float* __restrict__ bf) {
    int d = threadIdx.x;
    if (d >= 128) return;
    float acc = tok_b[d];
    for (int c = 0; c < 128; ++c)
        acc += (tok_w[d * 512 + c] + tok_w[d * 512 + 128 + c]) * nl_b[c];
    for (int c = 0; c < 128; ++c)
        acc += tok_w[d * 512 + 256 + c] * el_b[c];
    bf[d] = acc;
}

__device__ __forceinline__ int self_node(int t, const int* src, const int* dst, const int* neg) {
    if (t < NB) return src[t];
    if (t < 2 * NB) return dst[t - NB];
    return neg[t - 2 * NB];
}

__global__ void count_k(const int* __restrict__ src, const int* __restrict__ dst,
                        const int* __restrict__ neg, int* __restrict__ cnt) {
    int t = blockIdx.x * 256 + threadIdx.x;
    if (t >= NTOK) return;
    atomicAdd(&cnt[self_node(t, src, dst, neg)], 1);
}

__global__ __launch_bounds__(1024) void scan_k(const int* __restrict__ cnt,
                                               int* __restrict__ starts) {
    __shared__ int ps[1024];
    int t = threadIdx.x;
    const int PER = 20;
    int base = t * PER;
    int loc[PER];
    int s = 0;
#pragma unroll
    for (int k = 0; k < PER; ++k) {
        int i = base + k;
        int v = (i < NNODES) ? cnt[i] : 0;
        loc[k] = s;
        s += v;
    }
    ps[t] = s;
    __syncthreads();
    for (int off = 1; off < 1024; off <<= 1) {
        int v = (t >= off) ? ps[t - off] : 0;
        __syncthreads();
        ps[t] += v;
        __syncthreads();
    }
    int offv = (t > 0) ? ps[t - 1] : 0;
#pragma unroll
    for (int k = 0; k < PER; ++k) {
        int i = base + k;
        if (i < NNODES) starts[i] = offv + loc[k];
    }
}

__global__ void scatter_k(const int* __restrict__ src, const int* __restrict__ dst,
                          const int* __restrict__ neg, const int* __restrict__ starts,
                          int* __restrict__ cursor, int* __restrict__ order) {
    int t = blockIdx.x * 256 + threadIdx.x;
    if (t >= NTOK) return;
    int node = self_node(t, src, dst, neg);
    int p = atomicAdd(&cursor[node], 1);
    order[starts[node] + p] = t;
}

__global__ void aemb_k(const int* __restrict__ eidx, const float* __restrict__ ts,
                       const float* __restrict__ ef, const float* __restrict__ tw,
                       const float* __restrict__ tb, __hip_bfloat16* __restrict__ Aemb) {
    int idx = blockIdx.x * 256 + threadIdx.x;
    if (idx >= NB * 192) return;
    int m = idx / 192, j = idx % 192;
    float v;
    if (j < 64) v = ef[(size_t)eidx[m] * 64 + j];
    else { int c = j - 64; v = cosf(ts[m] * tw[c] + tb[c]); }
    Aemb[idx] = __float2bfloat16(v);
}

// x[p] = relu(gathered sum) in SORTED order; h[p] = LN1_l0(x[p])
__global__ __launch_bounds__(256) void asm_emb_k(
    const int* __restrict__ order, const int* __restrict__ src, const int* __restrict__ dst,
    const int* __restrict__ neg, const float* __restrict__ P12, const float* __restrict__ E,
    const float* __restrict__ s, const float* __restrict__ b,
    float* __restrict__ x, __hip_bfloat16* __restrict__ h) {
    int p = blockIdx.x * 4 + (threadIdx.x >> 6);
    int lane = threadIdx.x & 63;
    int t = order[p];
    int m, self, other;
    if (t < NB) { m = t; self = src[m]; other = dst[m]; }
    else if (t < 2 * NB) { m = t - NB; self = dst[m]; other = src[m]; }
    else { m = t - 2 * NB; self = neg[m]; other = src[m]; }
    int d0 = lane, d1 = lane + 64;
    float v0 = P12[(size_t)self * 256 + d0] + P12[(size_t)other * 256 + 128 + d0] +
               E[(size_t)m * 128 + d0];
    float v1 = P12[(size_t)self * 256 + d1] + P12[(size_t)other * 256 + 128 + d1] +
               E[(size_t)m * 128 + d1];
    v0 = fmaxf(v0, 0.f);
    v1 = fmaxf(v1, 0.f);
    float sum = v0 + v1;
#pragma unroll
    for (int off = 32; off; off >>= 1) sum += __shfl_xor(sum, off, 64);
    float mean = sum * (1.f / 128.f);
    float c0 = v0 - mean, c1 = v1 - mean;
    float vs = c0 * c0 + c1 * c1;
#pragma unroll
    for (int off = 32; off; off >>= 1) vs += __shfl_xor(vs, off, 64);
    float inv = rsqrtf(vs * (1.f / 128.f) + 1e-5f);
    x[(size_t)p * 128 + d0] = v0;
    x[(size_t)p * 128 + d1] = v1;
    h[(size_t)p * 128 + d0] = __float2bfloat16(c0 * inv * s[d0] + b[d0]);
    h[(size_t)p * 128 + d1] = __float2bfloat16(c1 * inv * s[d1] + b[d1]);
}

// ---------------- fast gelu ----------------
__device__ __forceinline__ float gelu_f(float v) {
    float ax = fabsf(v) * 0.70710678118654752f;
    float t = 1.f / (1.f + 0.3275911f * ax);
    float poly = ((((1.061405429f * t - 1.453152027f) * t + 1.421413741f) * t -
                   0.284496736f) * t + 0.254829592f) * t;
    float erf_ax = 1.f - poly * __expf(-ax * ax);
    float erfv = (v < 0.f) ? -erf_ax : erf_ax;
    return 0.5f * v * (1.f + erfv);
}

// ---------------- modes ----------------
#define G_F32 0
#define G_BF16 1
#define G_ADD_LN 3

// ---------------- BK=32 TRIPLE-buffered single-barrier pipelined GEMM ----------------
template <int MODE>
__global__ __launch_bounds__(256, 3) void gemm5_k(
    const __hip_bfloat16* __restrict__ A, const __hip_bfloat16* __restrict__ B,
    const float* __restrict__ bias, float* __restrict__ x,
    const float* __restrict__ lns, const float* __restrict__ lnb,
    __hip_bfloat16* __restrict__ hout, float* __restrict__ Cf, int N, int K) {
    __shared__ __align__(16) __hip_bfloat16 sA[3 * 128 * 32];
    __shared__ __align__(16) __hip_bfloat16 sB[3 * 128 * 32];
    __shared__ float redS[2][128];
    __shared__ float redS2[2][128];
    int tid = threadIdx.x;
    int lane = tid & 63, wid = tid >> 6;
    int wm = wid & 1, wn = wid >> 1;
    int mBase = blockIdx.x * 128, nBase = blockIdx.y * 128;
    f32x4 acc[4][4];
#pragma unroll
    for (int i = 0; i < 4; ++i)
#pragma unroll
        for (int j = 0; j < 4; ++j) {
            f32x4 z = {0.f, 0.f, 0.f, 0.f};
            acc[i][j] = z;
        }

    auto stage = [&](int buf, int k0) {
#pragma unroll
        for (int i = 0; i < 2; ++i) {
            int cid = i * 256 + tid;
            int row = cid >> 2, slotS = cid & 3;
            int slotG = slotS ^ ((row & 3) ^ ((row >> 2) & 3));
            const __hip_bfloat16* ga = A + (size_t)(mBase + row) * K + k0 + slotG * 8;
            const __hip_bfloat16* gb = B + (size_t)(nBase + row) * K + k0 + slotG * 8;
            __builtin_amdgcn_global_load_lds(
                (gbl_t*)ga, (lds_t*)&sA[buf * 4096 + (cid & ~63) * 8], 16, 0, 0);
            __builtin_amdgcn_global_load_lds(
                (gbl_t*)gb, (lds_t*)&sB[buf * 4096 + (cid & ~63) * 8], 16, 0, 0);
        }
    };

    int nt = K >> 5;
    stage(0, 0);
    int cur = 0;
    for (int t = 0; t < nt; ++t) {
        int nxt = cur + 1;
        if (nxt == 3) nxt = 0;
        if (t + 1 < nt) {
            stage(nxt, (t + 1) << 5);
            asm volatile("s_waitcnt vmcnt(4)" ::: "memory");
        } else {
            asm volatile("s_waitcnt vmcnt(0)" ::: "memory");
        }
        __builtin_amdgcn_s_barrier();
        __builtin_amdgcn_sched_barrier(0);
        const bf16x8* AsV = reinterpret_cast<const bf16x8*>(sA + cur * 4096);
        const bf16x8* BsV = reinterpret_cast<const bf16x8*>(sB + cur * 4096);
        bf16x8 a[4], b[4];
        int kvec = lane >> 4;
#pragma unroll
        for (int f = 0; f < 4; ++f) {
            int ra = wm * 64 + f * 16 + (lane & 15);
            a[f] = AsV[ra * 4 + (kvec ^ ((ra & 3) ^ ((ra >> 2) & 3)))];
            int rb = wn * 64 + f * 16 + (lane & 15);
            b[f] = BsV[rb * 4 + (kvec ^ ((rb & 3) ^ ((rb >> 2) & 3)))];
        }
        __builtin_amdgcn_s_setprio(1);
#pragma unroll
        for (int fm = 0; fm < 4; ++fm)
#pragma unroll
            for (int fn = 0; fn < 4; ++fn)
                acc[fm][fn] = __builtin_amdgcn_mfma_f32_16x16x32_bf16(
                    a[fm], b[fn], acc[fm][fn], 0, 0, 0);
        __builtin_amdgcn_s_setprio(0);
        cur = nxt;
    }

    if (MODE == G_F32 || MODE == G_BF16) {
        int colBase = nBase + wn * 64;
#pragma unroll
        for (int fm = 0; fm < 4; ++fm) {
            int row0 = mBase + wm * 64 + fm * 16 + (lane >> 4) * 4;
#pragma unroll
            for (int fn = 0; fn < 4; ++fn) {
                int col = colBase + fn * 16 + (lane & 15);
                float bv = bias ? bias[col] : 0.f;
#pragma unroll
                for (int j = 0; j < 4; ++j) {
                    float v = acc[fm][fn][j] + bv;
                    if (MODE == G_F32) Cf[(size_t)(row0 + j) * N + col] = v;
                    else hout[(size_t)(row0 + j) * N + col] = __float2bfloat16(v);
                }
            }
        }
    } else {
        // G_ADD_LN: N==128, nBase==0: residual add into x, then LN
#pragma unroll
        for (int fm = 0; fm < 4; ++fm) {
            int rl0 = wm * 64 + fm * 16 + (lane >> 4) * 4;
#pragma unroll
            for (int fn = 0; fn < 4; ++fn) {
                int col = wn * 64 + fn * 16 + (lane & 15);
                float bv = bias[col];
#pragma unroll
                for (int j = 0; j < 4; ++j) {
                    size_t off = (size_t)(mBase + rl0 + j) * 128 + col;
                    float v = acc[fm][fn][j] + bv + x[off];
                    x[off] = v;
                    acc[fm][fn][j] = v;
                }
            }
        }
#pragma unroll
        for (int fm = 0; fm < 4; ++fm) {
#pragma unroll
            for (int j = 0; j < 4; ++j) {
                float s1 = 0.f, s2 = 0.f;
#pragma unroll
                for (int fn = 0; fn < 4; ++fn) {
                    float v = acc[fm][fn][j];
                    s1 += v;
                    s2 += v * v;
                }
#pragma unroll
                for (int off = 1; off < 16; off <<= 1) {
                    s1 += __shfl_xor(s1, off, 64);
                    s2 += __shfl_xor(s2, off, 64);
                }
                if ((lane & 15) == 0) {
                    int rl = wm * 64 + fm * 16 + (lane >> 4) * 4 + j;
                    redS[wn][rl] = s1;
                    redS2[wn][rl] = s2;
                }
            }
        }
        __syncthreads();
#pragma unroll
        for (int fm = 0; fm < 4; ++fm) {
            int rl0 = wm * 64 + fm * 16 + (lane >> 4) * 4;
#pragma unroll
            for (int j = 0; j < 4; ++j) {
                int rl = rl0 + j;
                float mean = (redS[0][rl] + redS[1][rl]) * (1.f / 128.f);
                float var = (redS2[0][rl] + redS2[1][rl]) * (1.f / 128.f) - mean * mean;
                float inv = rsqrtf(var + 1e-5f);
#pragma unroll
                for (int fn = 0; fn < 4; ++fn) {
                    int col = wn * 64 + fn * 16 + (lane & 15);
                    float c = (acc[fm][fn][j] - mean) * inv;
                    hout[(size_t)(mBase + rl) * 128 + col] =
                        __float2bfloat16(c * lns[col] + lnb[col]);
                }
            }
        }
    }
}

// ---------------- fused FFN: x += gelu(h@W1^T+b1)@W2p^T + b2; h' = LN(x) / bf16 ----------------
// 16 chunks of 32 ff; u passes gemm1->gemm2 in registers. LDS 34KB -> 4 blocks/CU.
template <bool DO_LN>
__global__ __launch_bounds__(256, 4) void ffn_k(
    const __hip_bfloat16* __restrict__ h, const __hip_bfloat16* __restrict__ W1,
    const float* __restrict__ b1, const __hip_bfloat16* __restrict__ W2p,
    const float* __restrict__ b2, float* __restrict__ x,
    const float* __restrict__ lns, const float* __restrict__ lnb,
    __hip_bfloat16* __restrict__ hout) {
    __shared__ __align__(16) __hip_bfloat16 w1s[2][32 * 128];
    __shared__ __align__(16) __hip_bfloat16 w2s[2][128 * 32];
    __shared__ float b1s[512];
    int tid = threadIdx.x;
    int lane = tid & 63, wid = tid >> 6;
    int li = lane & 15, q = lane >> 4;
    int mBase = blockIdx.x * 128;

    b1s[tid] = b1[tid];
    b1s[256 + tid] = b1[256 + tid];

    // h fragments in registers (reused for all chunks)
    bf16x8 hf[2][4];
#pragma unroll
    for (int t = 0; t < 2; ++t)
#pragma unroll
        for (int kk = 0; kk < 4; ++kk)
            hf[t][kk] = *reinterpret_cast<const bf16x8*>(
                h + (size_t)(mBase + wid * 32 + t * 16 + li) * 128 + (kk * 4 + q) * 8);

    auto stageW = [&](int buf, int c) {
#pragma unroll
        for (int i = 0; i < 2; ++i) {
            int cid = i * 256 + tid;
            int r1 = cid >> 4, s1 = cid & 15;
            int g1 = s1 ^ (r1 & 15);
            __builtin_amdgcn_global_load_lds(
                (gbl_t*)(W1 + (size_t)(c * 32 + r1) * 128 + g1 * 8),
                (lds_t*)&w1s[buf][(cid & ~63) * 8], 16, 0, 0);
            int r2 = cid >> 2, s2 = cid & 3;
            int g2 = s2 ^ ((r2 & 3) ^ ((r2 >> 2) & 3));
            __builtin_amdgcn_global_load_lds(
                (gbl_t*)(W2p + (size_t)r2 * 512 + c * 32 + g2 * 8),
                (lds_t*)&w2s[buf][(cid & ~63) * 8], 16, 0, 0);
        }
    };

    f32x4 acc2[2][8];
#pragma unroll
    for (int t = 0; t < 2; ++t)
#pragma unroll
        for (int o = 0; o < 8; ++o) {
            f32x4 z = {0.f, 0.f, 0.f, 0.f};
            acc2[t][o] = z;
        }

    stageW(0, 0);
    for (int c = 0; c < 16; ++c) {
        if (c + 1 < 16) {
            stageW((c + 1) & 1, c + 1);
            asm volatile("s_waitcnt vmcnt(4) lgkmcnt(0)" ::: "memory");
        } else {
            asm volatile("s_waitcnt vmcnt(0) lgkmcnt(0)" ::: "memory");
        }
        __builtin_amdgcn_s_barrier();
        __builtin_amdgcn_sched_barrier(0);
        const bf16x8* W1v = reinterpret_cast<const bf16x8*>(w1s[c & 1]);
        const bf16x8* W2v = reinterpret_cast<const bf16x8*>(w2s[c & 1]);
        // gemm1: u^T[32 ff][32 tok] per wave (tok = lane&15 in C-cols)
        f32x4 acc1[2][2];
#pragma unroll
        for (int f = 0; f < 2; ++f)
#pragma unroll
            for (int t = 0; t < 2; ++t) {
                f32x4 z = {0.f, 0.f, 0.f, 0.f};
                acc1[f][t] = z;
            }
#pragma unroll
        for (int kk = 0; kk < 4; ++kk) {
            bf16x8 a[2];
#pragma unroll
            for (int f = 0; f < 2; ++f) {
                int r = f * 16 + li;
                a[f] = W1v[r * 16 + ((kk * 4 + q) ^ (r & 15))];
            }
            __builtin_amdgcn_s_setprio(1);
#pragma unroll
            for (int f = 0; f < 2; ++f)
#pragma unroll
                for (int t = 0; t < 2; ++t)
                    acc1[f][t] = __builtin_amdgcn_mfma_f32_16x16x32_bf16(
                        a[f], hf[t][kk], acc1[f][t], 0, 0, 0);
            __builtin_amdgcn_s_setprio(0);
        }
        // gelu + pack to bf16 A-frags, then gemm2 (one 32-wide k-chunk)
        bf16x8 uf[2];
#pragma unroll
        for (int t = 0; t < 2; ++t) {
#pragma unroll
            for (int e = 0; e < 8; ++e) {
                int f = e >> 2;
                float v = acc1[f][t][e & 3] + b1s[c * 32 + f * 16 + q * 4 + (e & 3)];
                v = gelu_f(v);
                __hip_bfloat16 bb = __float2bfloat16(v);
                uf[t][e] = *reinterpret_cast<short*>(&bb);
            }
        }
#pragma unroll
        for (int o = 0; o < 8; ++o) {
            int rb = o * 16 + li;
            bf16x8 w2f = W2v[rb * 4 + (q ^ ((rb & 3) ^ ((rb >> 2) & 3)))];
#pragma unroll
            for (int t = 0; t < 2; ++t)
                acc2[t][o] = __builtin_amdgcn_mfma_f32_16x16x32_bf16(
                    uf[t], w2f, acc2[t][o], 0, 0, 0);
        }
        __builtin_amdgcn_s_barrier();
    }

    // epilogue: bias + residual (+ optional x write) + wave-local LN
#pragma unroll
    for (int t = 0; t < 2; ++t) {
#pragma unroll
        for (int j = 0; j < 4; ++j) {
            int row = mBase + wid * 32 + t * 16 + q * 4 + j;
            float s1 = 0.f, s2 = 0.f;
#pragma unroll
            for (int o = 0; o < 8; ++o) {
                int col = o * 16 + li;
                size_t off = (size_t)row * 128 + col;
                float v = acc2[t][o][j] + b2[col] + x[off];
                if (DO_LN) x[off] = v;
                acc2[t][o][j] = v;
                s1 += v;
                s2 += v * v;
            }
#pragma unroll
            for (int off2 = 1; off2 < 16; off2 <<= 1) {
                s1 += __shfl_xor(s1, off2, 64);
                s2 += __shfl_xor(s2, off2, 64);
            }
            if (DO_LN) {
                float mean = s1 * (1.f / 128.f);
                float var = s2 * (1.f / 128.f) - mean * mean;
                float inv = rsqrtf(var + 1e-5f);
#pragma unroll
                for (int o = 0; o < 8; ++o) {
                    int col = o * 16 + li;
                    float cc = (acc2[t][o][j] - mean) * inv;
                    hout[(size_t)row * 128 + col] =
                        __float2bfloat16(cc * lns[col] + lnb[col]);
                }
            } else {
#pragma unroll
                for (int o = 0; o < 8; ++o) {
                    int col = o * 16 + li;
                    hout[(size_t)row * 128 + col] = __float2bfloat16(acc2[t][o][j]);
                }
            }
        }
    }
}

// ---------------- attention: wave per group, 4 queries in parallel ----------------
__global__ __launch_bounds__(256) void attn_k(
    const __hip_bfloat16* __restrict__ qkv, const int* __restrict__ starts,
    const int* __restrict__ cnt, __hip_bfloat16* __restrict__ o) {
    __shared__ float sc[4][4][4][MAXL];
    int wid = threadIdx.x >> 6, lane = threadIdx.x & 63;
    int node = blockIdx.x * 4 + wid;
    if (node >= NNODES) return;
    int st = starts[node];
    int len = cnt[node];
    if (len <= 0) return;
    if (len > MAXL) len = MAXL;
    int qs = lane >> 4, li = lane & 15, h = li >> 2;
    const float scale = 0.17677669529663687f;

    for (int qb = 0; qb < len; qb += 4) {
        int qi = qb + qs;
        bool act = qi < len;
        int qidx = act ? qi : len - 1;
        bf16x8 qv = *reinterpret_cast<const bf16x8*>(
            qkv + (size_t)(st + qidx) * 384 + li * 8);
        float qf[8];
#pragma unroll
        for (int e = 0; e < 8; ++e) qf[e] = b2f(qv[e]);
        for (int j = 0; j < len; ++j) {
            bf16x8 kv = *reinterpret_cast<const bf16x8*>(
                qkv + (size_t)(st + j) * 384 + 128 + li * 8);
            float d = 0.f;
#pragma unroll
            for (int e = 0; e < 8; ++e) d += qf[e] * b2f(kv[e]);
            d += __shfl_xor(d, 1, 64);
            d += __shfl_xor(d, 2, 64);
            if ((li & 3) == 0) sc[wid][qs][h][j] = d * scale;
        }
        float mx = -1e30f;
        for (int j = li & 3; j < len; j += 4) mx = fmaxf(mx, sc[wid][qs][h][j]);
        mx = fmaxf(mx, __shfl_xor(mx, 1, 64));
        mx = fmaxf(mx, __shfl_xor(mx, 2, 64));
        float ssum = 0.f;
        for (int j = li & 3; j < len; j += 4) {
            float e = __expf(sc[wid][qs][h][j] - mx);
            sc[wid][qs][h][j] = e;
            ssum += e;
        }
        ssum += __shfl_xor(ssum, 1, 64);
        ssum += __shfl_xor(ssum, 2, 64);
        float sinv = 1.f / ssum;
        float accv[8] = {0.f, 0.f, 0.f, 0.f, 0.f, 0.f, 0.f, 0.f};
        for (int j = 0; j < len; ++j) {
            float p = sc[wid][qs][h][j];
            bf16x8 vv = *reinterpret_cast<const bf16x8*>(
                qkv + (size_t)(st + j) * 384 + 256 + li * 8);
#pragma unroll
            for (int e = 0; e < 8; ++e) accv[e] += p * b2f(vv[e]);
        }
        if (act) {
            bf16x8 ov;
#pragma unroll
            for (int e = 0; e < 8; ++e) {
                __hip_bfloat16 t = __float2bfloat16(accv[e] * sinv);
                ov[e] = *reinterpret_cast<short*>(&t);
            }
            *reinterpret_cast<bf16x8*>(o + (size_t)(st + qi) * 128 + li * 8) = ov;
        }
    }
}

// ---------------- p1 GEMM + relu + head (logits+softmax) ----------------
__global__ __launch_bounds__(256) void p1head_k(
    const __hip_bfloat16* __restrict__ A, const __hip_bfloat16* __restrict__ B,
    const float* __restrict__ bias, const float* __restrict__ p2w,
    const float* __restrict__ p2b, const int* __restrict__ order,
    float* __restrict__ out) {
    __shared__ __align__(16) char smem[65536];
    __shared__ float p2s[640];
    __shared__ float p2bs[5];
    float4* As4 = (float4*)smem;
    float4* Bs4 = (float4*)(smem + 16384);
    float* rowbuf = (float*)smem;
    int tid = threadIdx.x;
    for (int i = tid; i < 640; i += 256) p2s[i] = p2w[i];
    if (tid < 5) p2bs[tid] = p2b[tid];
    int lane = tid & 63, wid = tid >> 6;
    int wm = wid & 1, wn = wid >> 1;
    int mBase = blockIdx.x * 128;
    f32x4 acc[4][4];
#pragma unroll
    for (int i = 0; i < 4; ++i)
#pragma unroll
        for (int j = 0; j < 4; ++j) {
            f32x4 z = {0.f, 0.f, 0.f, 0.f};
            acc[i][j] = z;
        }
    bf16x8* AsV = reinterpret_cast<bf16x8*>(As4);
    bf16x8* BsV = reinterpret_cast<bf16x8*>(Bs4);
    for (int k0 = 0; k0 < 128; k0 += 64) {
#pragma unroll
        for (int i = 0; i < 4; ++i) {
            int cid = i * 256 + tid;
            int r = cid >> 3, c = cid & 7;
            int sidx = r * 8 + (c ^ (r & 7));
            As4[sidx] = *reinterpret_cast<const float4*>(A + (size_t)(mBase + r) * 128 + k0 + c * 8);
            Bs4[sidx] = *reinterpret_cast<const float4*>(B + (size_t)r * 128 + k0 + c * 8);
        }
        __syncthreads();
#pragma unroll
        for (int kk = 0; kk < 2; ++kk) {
            bf16x8 a[4], bb[4];
            int ccol = kk * 4 + (lane >> 4);
#pragma unroll
            for (int f = 0; f < 4; ++f) {
                int ra = wm * 64 + f * 16 + (lane & 15);
                a[f] = AsV[ra * 8 + (ccol ^ (ra & 7))];
                int rb = wn * 64 + f * 16 + (lane & 15);
                bb[f] = BsV[rb * 8 + (ccol ^ (rb & 7))];
            }
#pragma unroll
            for (int fm = 0; fm < 4; ++fm)
#pragma unroll
                for (int fn = 0; fn < 4; ++fn)
                    acc[fm][fn] = __builtin_amdgcn_mfma_f32_16x16x32_bf16(
                        a[fm], bb[fn], acc[fm][fn], 0, 0, 0);
        }
        __syncthreads();
    }
#pragma unroll
    for (int fm = 0; fm < 4; ++fm) {
        int rl0 = wm * 64 + fm * 16 + (lane >> 4) * 4;
#pragma unroll
        for (int fn = 0; fn < 4; ++fn) {
            int col = wn * 64 + fn * 16 + (lane & 15);
            float bv = bias[col];
#pragma unroll
            for (int j = 0; j < 4; ++j) {
                int rl = rl0 + j;
                rowbuf[rl * 128 + (col ^ ((rl & 7) << 2))] = fmaxf(acc[fm][fn][j] + bv, 0.f);
            }
        }
    }
    __syncthreads();
    int row = tid >> 1, half = tid & 1;
    int swz = (row & 7) << 2;
    float lg[5] = {0.f, 0.f, 0.f, 0.f, 0.f};
    for (int i = 0; i < 64; ++i) {
        int col = half * 64 + i;
        float rv = rowbuf[row * 128 + (col ^ swz)];
#pragma unroll
        for (int k = 0; k < 5; ++k) lg[k] += rv * p2s[k * 128 + col];
    }
#pragma unroll
    for (int k = 0; k < 5; ++k) lg[k] += __shfl_xor(lg[k], 1, 64);
    if (half == 0) {
        float mx = -1e30f;
#pragma unroll
        for (int k = 0; k < 5; ++k) {
            lg[k] += p2bs[k];
            mx = fmaxf(mx, lg[k]);
        }
        float e[5], ssum = 0.f;
#pragma unroll
        for (int k = 0; k < 5; ++k) {
            e[k] = __expf(lg[k] - mx);
            ssum += e[k];
        }
        float si = 1.f / ssum;
        int t = order[mBase + row];
#pragma unroll
        for (int k = 0; k < 5; ++k) out[(size_t)t * 5 + k] = e[k] * si;
    }
}

// ---------------- host launch ----------------

extern "C" void kernel_launch(void* const* d_in, const int* in_sizes, int n_in,
                              void* d_out, int out_size, void* d_ws, size_t ws_size,
                              hipStream_t stream) {
    const int* src = (const int*)d_in[0];
    const int* dst = (const int*)d_in[1];
    const int* neg = (const int*)d_in[2];
    const int* eidx = (const int*)d_in[3];
    const float* ts = (const float*)d_in[4];
    const float* node_feats = (const float*)d_in[5];
    const float* edge_feats = (const float*)d_in[6];
    const float* node_lin_w = (const float*)d_in[7];
    const float* node_lin_b = (const float*)d_in[8];
    const float* edge_lin_w = (const float*)d_in[9];
    const float* edge_lin_b = (const float*)d_in[10];
    const float* time_w = (const float*)d_in[11];
    const float* time_b = (const float*)d_in[12];
    const float* tok_w = (const float*)d_in[13];
    const float* tok_b = (const float*)d_in[14];
    const float* qkv_w = (const float*)d_in[15];
    const float* qkv_b = (const float*)d_in[16];
    const float* attn_w = (const float*)d_in[17];
    const float* attn_b = (const float*)d_in[18];
    const float* ln1_s = (const float*)d_in[19];
    const float* ln1_b = (const float*)d_in[20];
    const float* ln2_s = (const float*)d_in[21];
    const float* ln2_b = (const float*)d_in[22];
    const float* ff1_w = (const float*)d_in[23];
    const float* ff1_b = (const float*)d_in[24];
    const float* ff2_w = (const float*)d_in[25];
    const float* ff2_b = (const float*)d_in[26];
    const float* p1_w = (const float*)d_in[27];
    const float* p1_b = (const float*)d_in[28];
    const float* p2_w = (const float*)d_in[29];
    const float* p2_b = (const float*)d_in[30];
    float* out = (float*)d_out;

    char* w = (char*)d_ws;
    auto alloc = [&](size_t bytes) {
        char* p = w;
        w += (bytes + 255) & ~(size_t)255;
        return p;
    };
    float* x = (float*)alloc((size_t)NTOK * 128 * 4);
    __hip_bfloat16* h = (__hip_bfloat16*)alloc((size_t)NTOK * 128 * 2);
    char* big = alloc((size_t)(NTOK + 64) * 512 * 2);
    __hip_bfloat16* qkvb = (__hip_bfloat16*)big;
    __hip_bfloat16* ob = (__hip_bfloat16*)(big + (size_t)(NTOK + 64) * 384 * 2);
    float* P12 = (float*)alloc((size_t)(NNODES + 96) * 256 * 4);
    float* E = (float*)alloc((size_t)NB * 128 * 4);
    __hip_bfloat16* Aemb = (__hip_bfloat16*)alloc((size_t)NB * 192 * 2);
    __hip_bfloat16* nfb = (__hip_bfloat16*)alloc((size_t)(NNODES + 96) * 128 * 2);
    __hip_bfloat16* A12 = (__hip_bfloat16*)alloc(256 * 128 * 2);
    __hip_bfloat16* AE = (__hip_bfloat16*)alloc(128 * 192 * 2);
    float* bfold = (float*)alloc(128 * 4);
    __hip_bfloat16* qkvwb = (__hip_bfloat16*)alloc(2 * 384 * 128 * 2);
    __hip_bfloat16* attnwb = (__hip_bfloat16*)alloc(2 * 128 * 128 * 2);
    __hip_bfloat16* ff1wb = (__hip_bfloat16*)alloc(2 * 512 * 128 * 2);
    __hip_bfloat16* w2pb = (__hip_bfloat16*)alloc(2 * 128 * 512 * 2);
    __hip_bfloat16* p1wb = (__hip_bfloat16*)alloc(128 * 128 * 2);
    int* cnt = (int*)alloc(NNODES * 4);
    int* starts = (int*)alloc(NNODES * 4);
    int* cursor = (int*)alloc(NNODES * 4);
    int* order = (int*)alloc(NTOK * 4);

    hipMemsetAsync(cnt, 0, NNODES * 4, stream);
    hipMemsetAsync(cursor, 0, NNODES * 4, stream);

    auto cvt = [&](const float* in, __hip_bfloat16* outp, int n) {
        int blocks = (n + 255) / 256;
        if (blocks > 2048) blocks = 2048;
        convert_k<<<blocks, 256, 0, stream>>>(in, outp, n);
    };
    cvt(node_feats, nfb, NNODES * 128);
    cvt(qkv_w, qkvwb, 2 * 384 * 128);
    cvt(attn_w, attnwb, 2 * 128 * 128);
    cvt(ff1_w, ff1wb, 2 * 512 * 128);
    cvtw2_k<<<(2 * 128 * 512 + 255) / 256, 256, 0, stream>>>(ff2_w, w2pb);
    cvt(p1_w, p1wb, 128 * 128);

    fold12_k<<<128, 256, 0, stream>>>(tok_w, node_lin_w, A12);
    foldE_k<<<96, 256, 0, stream>>>(tok_w, edge_lin_w, AE);
    foldb_k<<<1, 128, 0, stream>>>(tok_w, tok_b, node_lin_b, edge_lin_b, bfold);

    count_k<<<(NTOK + 255) / 256, 256, 0, stream>>>(src, dst, neg, cnt);
    scan_k<<<1, 1024, 0, stream>>>(cnt, starts);
    scatter_k<<<(NTOK + 255) / 256, 256, 0, stream>>>(src, dst, neg, starts, cursor, order);

    aemb_k<<<(NB * 192 + 255) / 256, 256, 0, stream>>>(eidx, ts, edge_feats, time_w, time_b, Aemb);

    gemm5_k<G_F32><<<dim3(157, 2), 256, 0, stream>>>(
        nfb, A12, nullptr, nullptr, nullptr, nullptr, nullptr, P12, 256, 128);
    gemm5_k<G_F32><<<dim3(256, 1), 256, 0, stream>>>(
        Aemb, AE, bfold, nullptr, nullptr, nullptr, nullptr, E, 128, 192);
    asm_emb_k<<<NTOK / 4, 256, 0, stream>>>(order, src, dst, neg, P12, E,
                                            ln1_s, ln1_b, x, h);

    const int gm = NTOK / 128;  // 768

    for (int l = 0; l < 2; ++l) {
        gemm5_k<G_BF16><<<dim3(gm, 3), 256, 0, stream>>>(
            h, qkvwb + (size_t)l * 384 * 128, qkv_b + l * 384,
            nullptr, nullptr, nullptr, qkvb, nullptr, 384, 128);
        attn_k<<<(NNODES + 3) / 4, 256, 0, stream>>>(qkvb, starts, cnt, ob);
        gemm5_k<G_ADD_LN><<<dim3(gm, 1), 256, 0, stream>>>(
            ob, attnwb + (size_t)l * 128 * 128, attn_b + l * 128,
            x, ln2_s + l * 128, ln2_b + l * 128, h, nullptr, 128, 128);
        if (l == 0)
            ffn_k<true><<<gm, 256, 0, stream>>>(
                h, ff1wb, ff1_b, w2pb, ff2_b, x, ln1_s + 128, ln1_b + 128, h);
        else
            ffn_k<false><<<gm, 256, 0, stream>>>(
                h, ff1wb + (size_t)512 * 128, ff1_b + 512, w2pb + (size_t)128 * 512,
                ff2_b + 128, x, nullptr, nullptr, h);
    }

    p1head_k<<<gm, 256, 0, stream>>>(h, p1wb, p1_b, p2_w, p2_b, order, out);
}

// Round 15
// 508.622 us; speedup vs baseline: 1.0860x; 1.0860x over previous
//
#include <hip/hip_runtime.h>
#include <hip/hip_bf16.h>
#include <math.h>

#define NB 32768
#define NTOK (3 * NB)
#define NNODES 20000
#define MAXL 64

typedef short bf16x8 __attribute__((ext_vector_type(8)));
typedef float f32x4 __attribute__((ext_vector_type(4)));

typedef __attribute__((address_space(3))) void lds_t;
typedef const __attribute__((address_space(1))) void gbl_t;

__device__ __forceinline__ float b2f(short s) {
    unsigned int u = ((unsigned int)(unsigned short)s) << 16;
    union { unsigned int u; float f; } c;
    c.u = u;
    return c.f;
}

// ---------------- small setup kernels ----------------

__global__ void convert_k(const float* __restrict__ in, __hip_bfloat16* __restrict__ out, int n) {
    int i = blockIdx.x * 256 + threadIdx.x;
    int stride = gridDim.x * 256;
    for (; i < n; i += stride) out[i] = __float2bfloat16(in[i]);
}

// ff2 weights with k-dim permuted within 32-blocks so gemm1's u^T C-frags feed
// gemm2's A-frags directly in registers: src = ((p>>2)&1)*16 + ((p>>3)<<2) + (p&3)
__global__ void cvtw2_k(const float* __restrict__ in, __hip_bfloat16* __restrict__ out) {
    int idx = blockIdx.x * 256 + threadIdx.x;
    if (idx >= 2 * 128 * 512) return;
    int row = idx >> 9, kk = idx & 511;
    int s = kk >> 5, p = kk & 31;
    int src = (s << 5) + ((p >> 2) & 1) * 16 + ((p >> 3) << 2) + (p & 3);
    out[idx] = __float2bfloat16(in[(size_t)row * 512 + src]);
}

__global__ void fold12_k(const float* __restrict__ tok_w, const float* __restrict__ nl_w,
                         __hip_bfloat16* __restrict__ A12) {
    int idx = blockIdx.x * 256 + threadIdx.x;
    if (idx >= 256 * 128) return;
    int n = idx >> 7, f = idx & 127;
    const float* tw = (n < 128) ? (tok_w + n * 512) : (tok_w + (n - 128) * 512 + 128);
    float acc = 0.f;
    for (int c = 0; c < 128; ++c) acc += tw[c] * nl_w[c * 128 + f];
    A12[idx] = __float2bfloat16(acc);
}

__global__ void foldE_k(const float* __restrict__ tok_w, const float* __restrict__ el_w,
                        __hip_bfloat16* __restrict__ AE) {
    int idx = blockIdx.x * 256 + threadIdx.x;
    if (idx >= 128 * 192) return;
    int d = idx / 192, j = idx % 192;
    float acc;
    if (j < 64) {
        acc = 0.f;
        for (int c = 0; c < 128; ++c) acc += tok_w[d * 512 + 256 + c] * el_w[c * 64 + j];
    } else {
        acc = tok_w[d * 512 + 384 + (j - 64)];
    }
    AE[idx] = __float2bfloat16(acc);
}

__global__ void foldb_k(const float* __restrict__ tok_w, const float* __restrict__ tok_b,
                        const float* __restrict__ nl_b, const float* __restrict__ el_b,
                        float* __restrict__ bf) {
    int d = threadIdx.x;
    if (d >= 128) return;
    float acc = tok_b[d];
    for (int c = 0; c < 128; ++c)
        acc += (tok_w[d * 512 + c] + tok_w[d * 512 + 128 + c]) * nl_b[c];
    for (int c = 0; c < 128; ++c)
        acc += tok_w[d * 512 + 256 + c] * el_b[c];
    bf[d] = acc;
}

__device__ __forceinline__ int self_node(int t, const int* src, const int* dst, const int* neg) {
    if (t < NB) return src[t];
    if (t < 2 * NB) return dst[t - NB];
    return neg[t - 2 * NB];
}

__global__ void count_k(const int* __restrict__ src, const int* __restrict__ dst,
                        const int* __restrict__ neg, int* __restrict__ cnt) {
    int t = blockIdx.x * 256 + threadIdx.x;
    if (t >= NTOK) return;
    atomicAdd(&cnt[self_node(t, src, dst, neg)], 1);
}

__global__ __launch_bounds__(1024) void scan_k(const int* __restrict__ cnt,
                                               int* __restrict__ starts) {
    __shared__ int ps[1024];
    int t = threadIdx.x;
    const int PER = 20;
    int base = t * PER;
    int loc[PER];
    int s = 0;
#pragma unroll
    for (int k = 0; k < PER; ++k) {
        int i = base + k;
        int v = (i < NNODES) ? cnt[i] : 0;
        loc[k] = s;
        s += v;
    }
    ps[t] = s;
    __syncthreads();
    for (int off = 1; off < 1024; off <<= 1) {
        int v = (t >= off) ? ps[t - off] : 0;
        __syncthreads();
        ps[t] += v;
        __syncthreads();
    }
    int offv = (t > 0) ? ps[t - 1] : 0;
#pragma unroll
    for (int k = 0; k < PER; ++k) {
        int i = base + k;
        if (i < NNODES) starts[i] = offv + loc[k];
    }
}

__global__ void scatter_k(const int* __restrict__ src, const int* __restrict__ dst,
                          const int* __restrict__ neg, const int* __restrict__ starts,
                          int* __restrict__ cursor, int* __restrict__ order) {
    int t = blockIdx.x * 256 + threadIdx.x;
    if (t >= NTOK) return;
    int node = self_node(t, src, dst, neg);
    int p = atomicAdd(&cursor[node], 1);
    order[starts[node] + p] = t;
}

__global__ void aemb_k(const int* __restrict__ eidx, const float* __restrict__ ts,
                       const float* __restrict__ ef, const float* __restrict__ tw,
                       const float* __restrict__ tb, __hip_bfloat16* __restrict__ Aemb) {
    int idx = blockIdx.x * 256 + threadIdx.x;
    if (idx >= NB * 192) return;
    int m = idx / 192, j = idx % 192;
    float v;
    if (j < 64) v = ef[(size_t)eidx[m] * 64 + j];
    else { int c = j - 64; v = cosf(ts[m] * tw[c] + tb[c]); }
    Aemb[idx] = __float2bfloat16(v);
}

// x[p] = relu(gathered sum) in SORTED order; h[p] = LN1_l0(x[p])
__global__ __launch_bounds__(256) void asm_emb_k(
    const int* __restrict__ order, const int* __restrict__ src, const int* __restrict__ dst,
    const int* __restrict__ neg, const float* __restrict__ P12, const float* __restrict__ E,
    const float* __restrict__ s, const float* __restrict__ b,
    float* __restrict__ x, __hip_bfloat16* __restrict__ h) {
    int p = blockIdx.x * 4 + (threadIdx.x >> 6);
    int lane = threadIdx.x & 63;
    int t = order[p];
    int m, self, other;
    if (t < NB) { m = t; self = src[m]; other = dst[m]; }
    else if (t < 2 * NB) { m = t - NB; self = dst[m]; other = src[m]; }
    else { m = t - 2 * NB; self = neg[m]; other = src[m]; }
    int d0 = lane, d1 = lane + 64;
    float v0 = P12[(size_t)self * 256 + d0] + P12[(size_t)other * 256 + 128 + d0] +
               E[(size_t)m * 128 + d0];
    float v1 = P12[(size_t)self * 256 + d1] + P12[(size_t)other * 256 + 128 + d1] +
               E[(size_t)m * 128 + d1];
    v0 = fmaxf(v0, 0.f);
    v1 = fmaxf(v1, 0.f);
    float sum = v0 + v1;
#pragma unroll
    for (int off = 32; off; off >>= 1) sum += __shfl_xor(sum, off, 64);
    float mean = sum * (1.f / 128.f);
    float c0 = v0 - mean, c1 = v1 - mean;
    float vs = c0 * c0 + c1 * c1;
#pragma unroll
    for (int off = 32; off; off >>= 1) vs += __shfl_xor(vs, off, 64);
    float inv = rsqrtf(vs * (1.f / 128.f) + 1e-5f);
    x[(size_t)p * 128 + d0] = v0;
    x[(size_t)p * 128 + d1] = v1;
    h[(size_t)p * 128 + d0] = __float2bfloat16(c0 * inv * s[d0] + b[d0]);
    h[(size_t)p * 128 + d1] = __float2bfloat16(c1 * inv * s[d1] + b[d1]);
}

// ---------------- fast gelu ----------------
__device__ __forceinline__ float gelu_f(float v) {
    float ax = fabsf(v) * 0.70710678118654752f;
    float t = 1.f / (1.f + 0.3275911f * ax);
    float poly = ((((1.061405429f * t - 1.453152027f) * t + 1.421413741f) * t -
                   0.284496736f) * t + 0.254829592f) * t;
    float erf_ax = 1.f - poly * __expf(-ax * ax);
    float erfv = (v < 0.f) ? -erf_ax : erf_ax;
    return 0.5f * v * (1.f + erfv);
}

// ---------------- modes ----------------
#define G_F32 0
#define G_BF16 1
#define G_ADD_LN 3

// ---------------- BK=32 TRIPLE-buffered single-barrier pipelined GEMM ----------------
template <int MODE>
__global__ __launch_bounds__(256, 3) void gemm5_k(
    const __hip_bfloat16* __restrict__ A, const __hip_bfloat16* __restrict__ B,
    const float* __restrict__ bias, float* __restrict__ x,
    const float* __restrict__ lns, const float* __restrict__ lnb,
    __hip_bfloat16* __restrict__ hout, float* __restrict__ Cf, int N, int K) {
    __shared__ __align__(16) __hip_bfloat16 sA[3 * 128 * 32];
    __shared__ __align__(16) __hip_bfloat16 sB[3 * 128 * 32];
    __shared__ float redS[2][128];
    __shared__ float redS2[2][128];
    int tid = threadIdx.x;
    int lane = tid & 63, wid = tid >> 6;
    int wm = wid & 1, wn = wid >> 1;
    int mBase = blockIdx.x * 128, nBase = blockIdx.y * 128;
    f32x4 acc[4][4];
#pragma unroll
    for (int i = 0; i < 4; ++i)
#pragma unroll
        for (int j = 0; j < 4; ++j) {
            f32x4 z = {0.f, 0.f, 0.f, 0.f};
            acc[i][j] = z;
        }

    auto stage = [&](int buf, int k0) {
#pragma unroll
        for (int i = 0; i < 2; ++i) {
            int cid = i * 256 + tid;
            int row = cid >> 2, slotS = cid & 3;
            int slotG = slotS ^ ((row & 3) ^ ((row >> 2) & 3));
            const __hip_bfloat16* ga = A + (size_t)(mBase + row) * K + k0 + slotG * 8;
            const __hip_bfloat16* gb = B + (size_t)(nBase + row) * K + k0 + slotG * 8;
            __builtin_amdgcn_global_load_lds(
                (gbl_t*)ga, (lds_t*)&sA[buf * 4096 + (cid & ~63) * 8], 16, 0, 0);
            __builtin_amdgcn_global_load_lds(
                (gbl_t*)gb, (lds_t*)&sB[buf * 4096 + (cid & ~63) * 8], 16, 0, 0);
        }
    };

    int nt = K >> 5;
    stage(0, 0);
    int cur = 0;
    for (int t = 0; t < nt; ++t) {
        int nxt = cur + 1;
        if (nxt == 3) nxt = 0;
        if (t + 1 < nt) {
            stage(nxt, (t + 1) << 5);
            asm volatile("s_waitcnt vmcnt(4)" ::: "memory");
        } else {
            asm volatile("s_waitcnt vmcnt(0)" ::: "memory");
        }
        __builtin_amdgcn_s_barrier();
        __builtin_amdgcn_sched_barrier(0);
        const bf16x8* AsV = reinterpret_cast<const bf16x8*>(sA + cur * 4096);
        const bf16x8* BsV = reinterpret_cast<const bf16x8*>(sB + cur * 4096);
        bf16x8 a[4], b[4];
        int kvec = lane >> 4;
#pragma unroll
        for (int f = 0; f < 4; ++f) {
            int ra = wm * 64 + f * 16 + (lane & 15);
            a[f] = AsV[ra * 4 + (kvec ^ ((ra & 3) ^ ((ra >> 2) & 3)))];
            int rb = wn * 64 + f * 16 + (lane & 15);
            b[f] = BsV[rb * 4 + (kvec ^ ((rb & 3) ^ ((rb >> 2) & 3)))];
        }
        __builtin_amdgcn_s_setprio(1);
#pragma unroll
        for (int fm = 0; fm < 4; ++fm)
#pragma unroll
            for (int fn = 0; fn < 4; ++fn)
                acc[fm][fn] = __builtin_amdgcn_mfma_f32_16x16x32_bf16(
                    a[fm], b[fn], acc[fm][fn], 0, 0, 0);
        __builtin_amdgcn_s_setprio(0);
        cur = nxt;
    }

    if (MODE == G_F32 || MODE == G_BF16) {
        int colBase = nBase + wn * 64;
#pragma unroll
        for (int fm = 0; fm < 4; ++fm) {
            int row0 = mBase + wm * 64 + fm * 16 + (lane >> 4) * 4;
#pragma unroll
            for (int fn = 0; fn < 4; ++fn) {
                int col = colBase + fn * 16 + (lane & 15);
                float bv = bias ? bias[col] : 0.f;
#pragma unroll
                for (int j = 0; j < 4; ++j) {
                    float v = acc[fm][fn][j] + bv;
                    if (MODE == G_F32) Cf[(size_t)(row0 + j) * N + col] = v;
                    else hout[(size_t)(row0 + j) * N + col] = __float2bfloat16(v);
                }
            }
        }
    } else {
        // G_ADD_LN: N==128, nBase==0: residual add into x, then LN
#pragma unroll
        for (int fm = 0; fm < 4; ++fm) {
            int rl0 = wm * 64 + fm * 16 + (lane >> 4) * 4;
#pragma unroll
            for (int fn = 0; fn < 4; ++fn) {
                int col = wn * 64 + fn * 16 + (lane & 15);
                float bv = bias[col];
#pragma unroll
                for (int j = 0; j < 4; ++j) {
                    size_t off = (size_t)(mBase + rl0 + j) * 128 + col;
                    float v = acc[fm][fn][j] + bv + x[off];
                    x[off] = v;
                    acc[fm][fn][j] = v;
                }
            }
        }
#pragma unroll
        for (int fm = 0; fm < 4; ++fm) {
#pragma unroll
            for (int j = 0; j < 4; ++j) {
                float s1 = 0.f, s2 = 0.f;
#pragma unroll
                for (int fn = 0; fn < 4; ++fn) {
                    float v = acc[fm][fn][j];
                    s1 += v;
                    s2 += v * v;
                }
#pragma unroll
                for (int off = 1; off < 16; off <<= 1) {
                    s1 += __shfl_xor(s1, off, 64);
                    s2 += __shfl_xor(s2, off, 64);
                }
                if ((lane & 15) == 0) {
                    int rl = wm * 64 + fm * 16 + (lane >> 4) * 4 + j;
                    redS[wn][rl] = s1;
                    redS2[wn][rl] = s2;
                }
            }
        }
        __syncthreads();
#pragma unroll
        for (int fm = 0; fm < 4; ++fm) {
            int rl0 = wm * 64 + fm * 16 + (lane >> 4) * 4;
#pragma unroll
            for (int j = 0; j < 4; ++j) {
                int rl = rl0 + j;
                float mean = (redS[0][rl] + redS[1][rl]) * (1.f / 128.f);
                float var = (redS2[0][rl] + redS2[1][rl]) * (1.f / 128.f) - mean * mean;
                float inv = rsqrtf(var + 1e-5f);
#pragma unroll
                for (int fn = 0; fn < 4; ++fn) {
                    int col = wn * 64 + fn * 16 + (lane & 15);
                    float c = (acc[fm][fn][j] - mean) * inv;
                    hout[(size_t)(mBase + rl) * 128 + col] =
                        __float2bfloat16(c * lns[col] + lnb[col]);
                }
            }
        }
    }
}

// ---------------- fused FFN: x += gelu(h@W1^T+b1)@W2p^T + b2; h' = LN(x) / bf16 ----------------
// u passes gemm1->gemm2 entirely in registers via operand-swap + W2 k-permutation.
// Per block: 128 tok rows; 4 waves x 32 tok. 8 ff-chunks of 64, W double-buffered.
template <bool DO_LN>
__global__ __launch_bounds__(256, 2) void ffn_k(
    const __hip_bfloat16* __restrict__ h, const __hip_bfloat16* __restrict__ W1,
    const float* __restrict__ b1, const __hip_bfloat16* __restrict__ W2p,
    const float* __restrict__ b2, float* __restrict__ x,
    const float* __restrict__ lns, const float* __restrict__ lnb,
    __hip_bfloat16* __restrict__ hout) {
    __shared__ __align__(16) __hip_bfloat16 w1s[2][64 * 128];
    __shared__ __align__(16) __hip_bfloat16 w2s[2][128 * 64];
    __shared__ float b1s[512];
    int tid = threadIdx.x;
    int lane = tid & 63, wid = tid >> 6;
    int li = lane & 15, q = lane >> 4;
    int mBase = blockIdx.x * 128;

    b1s[tid] = b1[tid];
    b1s[256 + tid] = b1[256 + tid];

    // h fragments in registers (reused for all 8 chunks)
    bf16x8 hf[2][4];
#pragma unroll
    for (int t = 0; t < 2; ++t)
#pragma unroll
        for (int kk = 0; kk < 4; ++kk)
            hf[t][kk] = *reinterpret_cast<const bf16x8*>(
                h + (size_t)(mBase + wid * 32 + t * 16 + li) * 128 + (kk * 4 + q) * 8);

    auto stageW = [&](int buf, int c) {
#pragma unroll
        for (int i = 0; i < 4; ++i) {
            int cid = i * 256 + tid;
            int r1 = cid >> 4, s1 = cid & 15;
            int g1 = s1 ^ (r1 & 15);
            __builtin_amdgcn_global_load_lds(
                (gbl_t*)(W1 + (size_t)(c * 64 + r1) * 128 + g1 * 8),
                (lds_t*)&w1s[buf][(cid & ~63) * 8], 16, 0, 0);
            int r2 = cid >> 3, s2 = cid & 7;
            int g2 = s2 ^ (r2 & 7);
            __builtin_amdgcn_global_load_lds(
                (gbl_t*)(W2p + (size_t)r2 * 512 + c * 64 + g2 * 8),
                (lds_t*)&w2s[buf][(cid & ~63) * 8], 16, 0, 0);
        }
    };

    f32x4 acc2[2][8];
#pragma unroll
    for (int t = 0; t < 2; ++t)
#pragma unroll
        for (int o = 0; o < 8; ++o) {
            f32x4 z = {0.f, 0.f, 0.f, 0.f};
            acc2[t][o] = z;
        }

    stageW(0, 0);
    for (int c = 0; c < 8; ++c) {
        if (c + 1 < 8) {
            stageW((c + 1) & 1, c + 1);
            asm volatile("s_waitcnt vmcnt(8) lgkmcnt(0)" ::: "memory");
        } else {
            asm volatile("s_waitcnt vmcnt(0) lgkmcnt(0)" ::: "memory");
        }
        __builtin_amdgcn_s_barrier();
        __builtin_amdgcn_sched_barrier(0);
        const bf16x8* W1v = reinterpret_cast<const bf16x8*>(w1s[c & 1]);
        const bf16x8* W2v = reinterpret_cast<const bf16x8*>(w2s[c & 1]);
        // gemm1: u^T[64 ff][32 tok] per wave (tok = lane&15 in C-cols)
        f32x4 acc1[4][2];
#pragma unroll
        for (int f = 0; f < 4; ++f)
#pragma unroll
            for (int t = 0; t < 2; ++t) {
                f32x4 z = {0.f, 0.f, 0.f, 0.f};
                acc1[f][t] = z;
            }
#pragma unroll
        for (int kk = 0; kk < 4; ++kk) {
            bf16x8 a[4];
#pragma unroll
            for (int f = 0; f < 4; ++f) {
                int r = f * 16 + li;
                a[f] = W1v[r * 16 + ((kk * 4 + q) ^ (r & 15))];
            }
            __builtin_amdgcn_s_setprio(1);
#pragma unroll
            for (int f = 0; f < 4; ++f)
#pragma unroll
                for (int t = 0; t < 2; ++t)
                    acc1[f][t] = __builtin_amdgcn_mfma_f32_16x16x32_bf16(
                        a[f], hf[t][kk], acc1[f][t], 0, 0, 0);
            __builtin_amdgcn_s_setprio(0);
        }
        // gelu + pack to bf16 A-frags, then gemm2 over the two 32-wide k-chunks
#pragma unroll
        for (int s = 0; s < 2; ++s) {
            bf16x8 uf[2];
#pragma unroll
            for (int t = 0; t < 2; ++t) {
#pragma unroll
                for (int e = 0; e < 8; ++e) {
                    int f = 2 * s + (e >> 2);
                    float v = acc1[f][t][e & 3] + b1s[c * 64 + f * 16 + q * 4 + (e & 3)];
                    v = gelu_f(v);
                    __hip_bfloat16 bb = __float2bfloat16(v);
                    uf[t][e] = *reinterpret_cast<short*>(&bb);
                }
            }
#pragma unroll
            for (int o = 0; o < 8; ++o) {
                int rb = o * 16 + li;
                bf16x8 w2f = W2v[rb * 8 + ((s * 4 + q) ^ (rb & 7))];
#pragma unroll
                for (int t = 0; t < 2; ++t)
                    acc2[t][o] = __builtin_amdgcn_mfma_f32_16x16x32_bf16(
                        uf[t], w2f, acc2[t][o], 0, 0, 0);
            }
        }
        __builtin_amdgcn_s_barrier();
    }

    // epilogue: bias + residual (+ optional x write) + wave-local LN
#pragma unroll
    for (int t = 0; t < 2; ++t) {
#pragma unroll
        for (int j = 0; j < 4; ++j) {
            int row = mBase + wid * 32 + t * 16 + q * 4 + j;
            float s1 = 0.f, s2 = 0.f;
#pragma unroll
            for (int o = 0; o < 8; ++o) {
                int col = o * 16 + li;
                size_t off = (size_t)row * 128 + col;
                float v = acc2[t][o][j] + b2[col] + x[off];
                if (DO_LN) x[off] = v;
                acc2[t][o][j] = v;
                s1 += v;
                s2 += v * v;
            }
#pragma unroll
            for (int off2 = 1; off2 < 16; off2 <<= 1) {
                s1 += __shfl_xor(s1, off2, 64);
                s2 += __shfl_xor(s2, off2, 64);
            }
            if (DO_LN) {
                float mean = s1 * (1.f / 128.f);
                float var = s2 * (1.f / 128.f) - mean * mean;
                float inv = rsqrtf(var + 1e-5f);
#pragma unroll
                for (int o = 0; o < 8; ++o) {
                    int col = o * 16 + li;
                    float cc = (acc2[t][o][j] - mean) * inv;
                    hout[(size_t)row * 128 + col] =
                        __float2bfloat16(cc * lns[col] + lnb[col]);
                }
            } else {
#pragma unroll
                for (int o = 0; o < 8; ++o) {
                    int col = o * 16 + li;
                    hout[(size_t)row * 128 + col] = __float2bfloat16(acc2[t][o][j]);
                }
            }
        }
    }
}

// ---------------- attention: wave per group, 4 queries in parallel ----------------
__global__ __launch_bounds__(256) void attn_k(
    const __hip_bfloat16* __restrict__ qkv, const int* __restrict__ starts,
    const int* __restrict__ cnt, __hip_bfloat16* __restrict__ o) {
    __shared__ float sc[4][4][4][MAXL];
    int wid = threadIdx.x >> 6, lane = threadIdx.x & 63;
    int node = blockIdx.x * 4 + wid;
    if (node >= NNODES) return;
    int st = starts[node];
    int len = cnt[node];
    if (len <= 0) return;
    if (len > MAXL) len = MAXL;
    int qs = lane >> 4, li = lane & 15, h = li >> 2;
    const float scale = 0.17677669529663687f;

    for (int qb = 0; qb < len; qb += 4) {
        int qi = qb + qs;
        bool act = qi < len;
        int qidx = act ? qi : len - 1;
        bf16x8 qv = *reinterpret_cast<const bf16x8*>(
            qkv + (size_t)(st + qidx) * 384 + li * 8);
        float qf[8];
#pragma unroll
        for (int e = 0; e < 8; ++e) qf[e] = b2f(qv[e]);
        for (int j = 0; j < len; ++j) {
            bf16x8 kv = *reinterpret_cast<const bf16x8*>(
                qkv + (size_t)(st + j) * 384 + 128 + li * 8);
            float d = 0.f;
#pragma unroll
            for (int e = 0; e < 8; ++e) d += qf[e] * b2f(kv[e]);
            d += __shfl_xor(d, 1, 64);
            d += __shfl_xor(d, 2, 64);
            if ((li & 3) == 0) sc[wid][qs][h][j] = d * scale;
        }
        float mx = -1e30f;
        for (int j = li & 3; j < len; j += 4) mx = fmaxf(mx, sc[wid][qs][h][j]);
        mx = fmaxf(mx, __shfl_xor(mx, 1, 64));
        mx = fmaxf(mx, __shfl_xor(mx, 2, 64));
        float ssum = 0.f;
        for (int j = li & 3; j < len; j += 4) {
            float e = __expf(sc[wid][qs][h][j] - mx);
            sc[wid][qs][h][j] = e;
            ssum += e;
        }
        ssum += __shfl_xor(ssum, 1, 64);
        ssum += __shfl_xor(ssum, 2, 64);
        float sinv = 1.f / ssum;
        float accv[8] = {0.f, 0.f, 0.f, 0.f, 0.f, 0.f, 0.f, 0.f};
        for (int j = 0; j < len; ++j) {
            float p = sc[wid][qs][h][j];
            bf16x8 vv = *reinterpret_cast<const bf16x8*>(
                qkv + (size_t)(st + j) * 384 + 256 + li * 8);
#pragma unroll
            for (int e = 0; e < 8; ++e) accv[e] += p * b2f(vv[e]);
        }
        if (act) {
            bf16x8 ov;
#pragma unroll
            for (int e = 0; e < 8; ++e) {
                __hip_bfloat16 t = __float2bfloat16(accv[e] * sinv);
                ov[e] = *reinterpret_cast<short*>(&t);
            }
            *reinterpret_cast<bf16x8*>(o + (size_t)(st + qi) * 128 + li * 8) = ov;
        }
    }
}

// ---------------- p1 GEMM + relu + head (logits+softmax) ----------------
__global__ __launch_bounds__(256) void p1head_k(
    const __hip_bfloat16* __restrict__ A, const __hip_bfloat16* __restrict__ B,
    const float* __restrict__ bias, const float* __restrict__ p2w,
    const float* __restrict__ p2b, const int* __restrict__ order,
    float* __restrict__ out) {
    __shared__ __align__(16) char smem[65536];
    __shared__ float p2s[640];
    __shared__ float p2bs[5];
    float4* As4 = (float4*)smem;
    float4* Bs4 = (float4*)(smem + 16384);
    float* rowbuf = (float*)smem;
    int tid = threadIdx.x;
    for (int i = tid; i < 640; i += 256) p2s[i] = p2w[i];
    if (tid < 5) p2bs[tid] = p2b[tid];
    int lane = tid & 63, wid = tid >> 6;
    int wm = wid & 1, wn = wid >> 1;
    int mBase = blockIdx.x * 128;
    f32x4 acc[4][4];
#pragma unroll
    for (int i = 0; i < 4; ++i)
#pragma unroll
        for (int j = 0; j < 4; ++j) {
            f32x4 z = {0.f, 0.f, 0.f, 0.f};
            acc[i][j] = z;
        }
    bf16x8* AsV = reinterpret_cast<bf16x8*>(As4);
    bf16x8* BsV = reinterpret_cast<bf16x8*>(Bs4);
    for (int k0 = 0; k0 < 128; k0 += 64) {
#pragma unroll
        for (int i = 0; i < 4; ++i) {
            int cid = i * 256 + tid;
            int r = cid >> 3, c = cid & 7;
            int sidx = r * 8 + (c ^ (r & 7));
            As4[sidx] = *reinterpret_cast<const float4*>(A + (size_t)(mBase + r) * 128 + k0 + c * 8);
            Bs4[sidx] = *reinterpret_cast<const float4*>(B + (size_t)r * 128 + k0 + c * 8);
        }
        __syncthreads();
#pragma unroll
        for (int kk = 0; kk < 2; ++kk) {
            bf16x8 a[4], bb[4];
            int ccol = kk * 4 + (lane >> 4);
#pragma unroll
            for (int f = 0; f < 4; ++f) {
                int ra = wm * 64 + f * 16 + (lane & 15);
                a[f] = AsV[ra * 8 + (ccol ^ (ra & 7))];
                int rb = wn * 64 + f * 16 + (lane & 15);
                bb[f] = BsV[rb * 8 + (ccol ^ (rb & 7))];
            }
#pragma unroll
            for (int fm = 0; fm < 4; ++fm)
#pragma unroll
                for (int fn = 0; fn < 4; ++fn)
                    acc[fm][fn] = __builtin_amdgcn_mfma_f32_16x16x32_bf16(
                        a[fm], bb[fn], acc[fm][fn], 0, 0, 0);
        }
        __syncthreads();
    }
#pragma unroll
    for (int fm = 0; fm < 4; ++fm) {
        int rl0 = wm * 64 + fm * 16 + (lane >> 4) * 4;
#pragma unroll
        for (int fn = 0; fn < 4; ++fn) {
            int col = wn * 64 + fn * 16 + (lane & 15);
            float bv = bias[col];
#pragma unroll
            for (int j = 0; j < 4; ++j) {
                int rl = rl0 + j;
                rowbuf[rl * 128 + (col ^ ((rl & 7) << 2))] = fmaxf(acc[fm][fn][j] + bv, 0.f);
            }
        }
    }
    __syncthreads();
    int row = tid >> 1, half = tid & 1;
    int swz = (row & 7) << 2;
    float lg[5] = {0.f, 0.f, 0.f, 0.f, 0.f};
    for (int i = 0; i < 64; ++i) {
        int col = half * 64 + i;
        float rv = rowbuf[row * 128 + (col ^ swz)];
#pragma unroll
        for (int k = 0; k < 5; ++k) lg[k] += rv * p2s[k * 128 + col];
    }
#pragma unroll
    for (int k = 0; k < 5; ++k) lg[k] += __shfl_xor(lg[k], 1, 64);
    if (half == 0) {
        float mx = -1e30f;
#pragma unroll
        for (int k = 0; k < 5; ++k) {
            lg[k] += p2bs[k];
            mx = fmaxf(mx, lg[k]);
        }
        float e[5], ssum = 0.f;
#pragma unroll
        for (int k = 0; k < 5; ++k) {
            e[k] = __expf(lg[k] - mx);
            ssum += e[k];
        }
        float si = 1.f / ssum;
        int t = order[mBase + row];
#pragma unroll
        for (int k = 0; k < 5; ++k) out[(size_t)t * 5 + k] = e[k] * si;
    }
}

// ---------------- host launch ----------------

extern "C" void kernel_launch(void* const* d_in, const int* in_sizes, int n_in,
                              void* d_out, int out_size, void* d_ws, size_t ws_size,
                              hipStream_t stream) {
    const int* src = (const int*)d_in[0];
    const int* dst = (const int*)d_in[1];
    const int* neg = (const int*)d_in[2];
    const int* eidx = (const int*)d_in[3];
    const float* ts = (const float*)d_in[4];
    const float* node_feats = (const float*)d_in[5];
    const float* edge_feats = (const float*)d_in[6];
    const float* node_lin_w = (const float*)d_in[7];
    const float* node_lin_b = (const float*)d_in[8];
    const float* edge_lin_w = (const float*)d_in[9];
    const float* edge_lin_b = (const float*)d_in[10];
    const float* time_w = (const float*)d_in[11];
    const float* time_b = (const float*)d_in[12];
    const float* tok_w = (const float*)d_in[13];
    const float* tok_b = (const float*)d_in[14];
    const float* qkv_w = (const float*)d_in[15];
    const float* qkv_b = (const float*)d_in[16];
    const float* attn_w = (const float*)d_in[17];
    const float* attn_b = (const float*)d_in[18];
    const float* ln1_s = (const float*)d_in[19];
    const float* ln1_b = (const float*)d_in[20];
    const float* ln2_s = (const float*)d_in[21];
    const float* ln2_b = (const float*)d_in[22];
    const float* ff1_w = (const float*)d_in[23];
    const float* ff1_b = (const float*)d_in[24];
    const float* ff2_w = (const float*)d_in[25];
    const float* ff2_b = (const float*)d_in[26];
    const float* p1_w = (const float*)d_in[27];
    const float* p1_b = (const float*)d_in[28];
    const float* p2_w = (const float*)d_in[29];
    const float* p2_b = (const float*)d_in[30];
    float* out = (float*)d_out;

    char* w = (char*)d_ws;
    auto alloc = [&](size_t bytes) {
        char* p = w;
        w += (bytes + 255) & ~(size_t)255;
        return p;
    };
    float* x = (float*)alloc((size_t)NTOK * 128 * 4);
    __hip_bfloat16* h = (__hip_bfloat16*)alloc((size_t)NTOK * 128 * 2);
    char* big = alloc((size_t)(NTOK + 64) * 512 * 2);
    __hip_bfloat16* qkvb = (__hip_bfloat16*)big;
    __hip_bfloat16* ob = (__hip_bfloat16*)(big + (size_t)(NTOK + 64) * 384 * 2);
    float* P12 = (float*)alloc((size_t)(NNODES + 96) * 256 * 4);
    float* E = (float*)alloc((size_t)NB * 128 * 4);
    __hip_bfloat16* Aemb = (__hip_bfloat16*)alloc((size_t)NB * 192 * 2);
    __hip_bfloat16* nfb = (__hip_bfloat16*)alloc((size_t)(NNODES + 96) * 128 * 2);
    __hip_bfloat16* A12 = (__hip_bfloat16*)alloc(256 * 128 * 2);
    __hip_bfloat16* AE = (__hip_bfloat16*)alloc(128 * 192 * 2);
    float* bfold = (float*)alloc(128 * 4);
    __hip_bfloat16* qkvwb = (__hip_bfloat16*)alloc(2 * 384 * 128 * 2);
    __hip_bfloat16* attnwb = (__hip_bfloat16*)alloc(2 * 128 * 128 * 2);
    __hip_bfloat16* ff1wb = (__hip_bfloat16*)alloc(2 * 512 * 128 * 2);
    __hip_bfloat16* w2pb = (__hip_bfloat16*)alloc(2 * 128 * 512 * 2);
    __hip_bfloat16* p1wb = (__hip_bfloat16*)alloc(128 * 128 * 2);
    int* cnt = (int*)alloc(NNODES * 4);
    int* starts = (int*)alloc(NNODES * 4);
    int* cursor = (int*)alloc(NNODES * 4);
    int* order = (int*)alloc(NTOK * 4);

    hipMemsetAsync(cnt, 0, NNODES * 4, stream);
    hipMemsetAsync(cursor, 0, NNODES * 4, stream);

    auto cvt = [&](const float* in, __hip_bfloat16* outp, int n) {
        int blocks = (n + 255) / 256;
        if (blocks > 2048) blocks = 2048;
        convert_k<<<blocks, 256, 0, stream>>>(in, outp, n);
    };
    cvt(node_feats, nfb, NNODES * 128);
    cvt(qkv_w, qkvwb, 2 * 384 * 128);
    cvt(attn_w, attnwb, 2 * 128 * 128);
    cvt(ff1_w, ff1wb, 2 * 512 * 128);
    cvtw2_k<<<(2 * 128 * 512 + 255) / 256, 256, 0, stream>>>(ff2_w, w2pb);
    cvt(p1_w, p1wb, 128 * 128);

    fold12_k<<<128, 256, 0, stream>>>(tok_w, node_lin_w, A12);
    foldE_k<<<96, 256, 0, stream>>>(tok_w, edge_lin_w, AE);
    foldb_k<<<1, 128, 0, stream>>>(tok_w, tok_b, node_lin_b, edge_lin_b, bfold);

    count_k<<<(NTOK + 255) / 256, 256, 0, stream>>>(src, dst, neg, cnt);
    scan_k<<<1, 1024, 0, stream>>>(cnt, starts);
    scatter_k<<<(NTOK + 255) / 256, 256, 0, stream>>>(src, dst, neg, starts, cursor, order);

    aemb_k<<<(NB * 192 + 255) / 256, 256, 0, stream>>>(eidx, ts, edge_feats, time_w, time_b, Aemb);

    gemm5_k<G_F32><<<dim3(157, 2), 256, 0, stream>>>(
        nfb, A12, nullptr, nullptr, nullptr, nullptr, nullptr, P12, 256, 128);
    gemm5_k<G_F32><<<dim3(256, 1), 256, 0, stream>>>(
        Aemb, AE, bfold, nullptr, nullptr, nullptr, nullptr, E, 128, 192);
    asm_emb_k<<<NTOK / 4, 256, 0, stream>>>(order, src, dst, neg, P12, E,
                                            ln1_s, ln1_b, x, h);

    const int gm = NTOK / 128;  // 768

    for (int l = 0; l < 2; ++l) {
        gemm5_k<G_BF16><<<dim3(gm, 3), 256, 0, stream>>>(
            h, qkvwb + (size_t)l * 384 * 128, qkv_b + l * 384,
            nullptr, nullptr, nullptr, qkvb, nullptr, 384, 128);
        attn_k<<<(NNODES + 3) / 4, 256, 0, stream>>>(qkvb, starts, cnt, ob);
        gemm5_k<G_ADD_LN><<<dim3(gm, 1), 256, 0, stream>>>(
            ob, attnwb + (size_t)l * 128 * 128, attn_b + l * 128,
            x, ln2_s + l * 128, ln2_b + l * 128, h, nullptr, 128, 128);
        if (l == 0)
            ffn_k<true><<<gm, 256, 0, stream>>>(
                h, ff1wb, ff1_b, w2pb, ff2_b, x, ln1_s + 128, ln1_b + 128, h);
        else
            ffn_k<false><<<gm, 256, 0, stream>>>(
                h, ff1wb + (size_t)512 * 128, ff1_b + 512, w2pb + (size_t)128 * 512,
                ff2_b + 128, x, nullptr, nullptr, h);
    }

    p1head_k<<<gm, 256, 0, stream>>>(h, p1wb, p1_b, p2_w, p2_b, order, out);
}